// Round 7
// baseline (359.657 us; speedup 1.0000x reference)
//
#include <hip/hip_runtime.h>
#include <hip/hip_bf16.h>
#include <type_traits>

// ---------- types / helpers ----------
using bf16x8 = __attribute__((ext_vector_type(8))) short;   // 8 bf16 in 4 VGPRs
using f32x4  = __attribute__((ext_vector_type(4))) float;
using u16x8  = __attribute__((ext_vector_type(8))) unsigned short;
using u32x4  = __attribute__((ext_vector_type(4))) unsigned int;

__device__ __forceinline__ float b2f(unsigned short u) {
    unsigned int x = ((unsigned int)u) << 16;
    return __builtin_bit_cast(float, x);
}
__device__ __forceinline__ unsigned short f2b(float f) {
    __hip_bfloat16 h = __float2bfloat16(f);   // RN
    return __builtin_bit_cast(unsigned short, h);
}

// async global->LDS, 16 B per lane; LDS dest is wave-uniform base + lane*16
__device__ __forceinline__ void async_copy16(const void* g, void* l) {
    __builtin_amdgcn_global_load_lds(
        (const __attribute__((address_space(1))) unsigned int*)g,
        (__attribute__((address_space(3))) unsigned int*)l, 16, 0, 0);
}

#define MFMA16(a, b, c) __builtin_amdgcn_mfma_f32_16x16x32_bf16(a, b, c, 0, 0, 0)

// ---------- f32 -> bf16 conversion (4 elems/thread) ----------
__global__ __launch_bounds__(256) void cvt_f32_to_bf16(
    const float* __restrict__ s, unsigned short* __restrict__ d, int n4)
{
    int i = blockIdx.x * blockDim.x + threadIdx.x;
    if (i >= n4) return;
    float4 v = ((const float4*)s)[i];
    ushort4 o;
    o.x = f2b(v.x); o.y = f2b(v.y); o.z = f2b(v.z); o.w = f2b(v.w);
    ((ushort4*)d)[i] = o;
}

// ---------- fused QKV GEMM: [Q|K|V] = x @ [wq;wk;wv]^T ----------
__global__ __launch_bounds__(256) void qkv_gemm(
    const unsigned short* __restrict__ A,    // M x 2048
    const unsigned short* __restrict__ Wq,   // 2048 x 2048
    const unsigned short* __restrict__ Wk,   // 512 x 2048
    const unsigned short* __restrict__ Wv,   // 512 x 2048
    unsigned short* __restrict__ Q,          // M x 2048
    unsigned short* __restrict__ Kk,         // M x 512
    unsigned short* __restrict__ V)          // M x 512
{
    const int K = 2048;
    constexpr int BK = 64;
    __shared__ unsigned short As[128 * BK];
    __shared__ unsigned short Bs[128 * BK];

    int tid  = threadIdx.x;
    int w    = tid >> 6;
    int lane = tid & 63;
    int idx  = lane & 15;
    int quad = lane >> 4;
    int wm   = (w >> 1) * 64;
    int wn   = (w & 1) * 64;

    int bm = blockIdx.x / 24;
    int bn = blockIdx.x - bm * 24;
    int m0 = bm * 128;

    const unsigned short* Bt;
    unsigned short* C;
    int Nc, n0;
    if (bn < 16)      { Bt = Wq + (size_t)bn * 128 * K;        C = Q;  Nc = 2048; n0 = bn * 128; }
    else if (bn < 20) { Bt = Wk + (size_t)(bn - 16) * 128 * K; C = Kk; Nc = 512;  n0 = (bn - 16) * 128; }
    else              { Bt = Wv + (size_t)(bn - 20) * 128 * K; C = V;  Nc = 512;  n0 = (bn - 20) * 128; }

    int srow   = lane >> 3;
    int schunk = (lane & 7) ^ srow;

    f32x4 acc[4][4];
    #pragma unroll
    for (int mi = 0; mi < 4; ++mi)
        #pragma unroll
        for (int ni = 0; ni < 4; ++ni) acc[mi][ni] = (f32x4){0.f, 0.f, 0.f, 0.f};

    for (int k0 = 0; k0 < K; k0 += BK) {
        #pragma unroll
        for (int i = 0; i < 4; ++i) {
            int cb = w * 4 + i;
            size_t goff = (size_t)(cb * 8 + srow) * K + k0 + schunk * 8;
            async_copy16(A + (size_t)m0 * K + goff, &As[cb * 512]);
            async_copy16(Bt + goff, &Bs[cb * 512]);
        }
        __syncthreads();

        #pragma unroll
        for (int ks = 0; ks < 2; ++ks) {
            bf16x8 af[4], bfr[4];
            #pragma unroll
            for (int mi = 0; mi < 4; ++mi) {
                int row = wm + mi * 16 + idx;
                af[mi] = *(const bf16x8*)&As[row * BK + (((ks * 4 + quad) ^ (row & 7)) * 8)];
            }
            #pragma unroll
            for (int ni = 0; ni < 4; ++ni) {
                int row = wn + ni * 16 + idx;
                bfr[ni] = *(const bf16x8*)&Bs[row * BK + (((ks * 4 + quad) ^ (row & 7)) * 8)];
            }
            #pragma unroll
            for (int mi = 0; mi < 4; ++mi)
                #pragma unroll
                for (int ni = 0; ni < 4; ++ni)
                    acc[mi][ni] = MFMA16(af[mi], bfr[ni], acc[mi][ni]);
        }
        __syncthreads();
    }

    #pragma unroll
    for (int mi = 0; mi < 4; ++mi) {
        #pragma unroll
        for (int r = 0; r < 4; ++r) {
            size_t row = (size_t)(m0 + wm + mi * 16 + quad * 4 + r);
            #pragma unroll
            for (int ni = 0; ni < 4; ++ni) {
                int col = n0 + wn + ni * 16 + idx;
                C[row * Nc + col] = f2b(acc[mi][ni][r]);
            }
        }
    }
}

// ---------- tiled GEMM: C[M,N] = A[M,K] * Bt[N,K]^T (wo projection) ----------
template <typename OutT>
__global__ __launch_bounds__(256) void gemm_tile(
    const unsigned short* __restrict__ A,
    const unsigned short* __restrict__ Bt,
    OutT* __restrict__ C,
    int M, int N, int K)
{
    constexpr int BK = 64;
    __shared__ unsigned short As[128 * BK];
    __shared__ unsigned short Bs[128 * BK];

    int tid  = threadIdx.x;
    int w    = tid >> 6;
    int lane = tid & 63;
    int idx  = lane & 15;
    int quad = lane >> 4;
    int wm   = (w >> 1) * 64;
    int wn   = (w & 1) * 64;

    int tilesN = N / 128;
    int bm = blockIdx.x / tilesN;
    int bn = blockIdx.x - bm * tilesN;
    int m0 = bm * 128, n0 = bn * 128;

    int srow   = lane >> 3;
    int schunk = (lane & 7) ^ srow;

    f32x4 acc[4][4];
    #pragma unroll
    for (int mi = 0; mi < 4; ++mi)
        #pragma unroll
        for (int ni = 0; ni < 4; ++ni) acc[mi][ni] = (f32x4){0.f, 0.f, 0.f, 0.f};

    for (int k0 = 0; k0 < K; k0 += BK) {
        #pragma unroll
        for (int i = 0; i < 4; ++i) {
            int cb = w * 4 + i;
            size_t goff = (size_t)(cb * 8 + srow) * K + k0 + schunk * 8;
            async_copy16(A  + (size_t)m0 * K + goff, &As[cb * 512]);
            async_copy16(Bt + (size_t)n0 * K + goff, &Bs[cb * 512]);
        }
        __syncthreads();

        #pragma unroll
        for (int ks = 0; ks < 2; ++ks) {
            bf16x8 af[4], bfr[4];
            #pragma unroll
            for (int mi = 0; mi < 4; ++mi) {
                int row = wm + mi * 16 + idx;
                af[mi] = *(const bf16x8*)&As[row * BK + (((ks * 4 + quad) ^ (row & 7)) * 8)];
            }
            #pragma unroll
            for (int ni = 0; ni < 4; ++ni) {
                int row = wn + ni * 16 + idx;
                bfr[ni] = *(const bf16x8*)&Bs[row * BK + (((ks * 4 + quad) ^ (row & 7)) * 8)];
            }
            #pragma unroll
            for (int mi = 0; mi < 4; ++mi)
                #pragma unroll
                for (int ni = 0; ni < 4; ++ni)
                    acc[mi][ni] = MFMA16(af[mi], bfr[ni], acc[mi][ni]);
        }
        __syncthreads();
    }

    #pragma unroll
    for (int mi = 0; mi < 4; ++mi) {
        #pragma unroll
        for (int r = 0; r < 4; ++r) {
            size_t row = (size_t)(m0 + wm + mi * 16 + quad * 4 + r);
            #pragma unroll
            for (int ni = 0; ni < 4; ++ni) {
                int col = n0 + wn + ni * 16 + idx;
                if constexpr (std::is_same_v<OutT, float>) {
                    C[row * N + col] = acc[mi][ni][r];
                } else {
                    C[row * N + col] = f2b(acc[mi][ni][r]);
                }
            }
        }
    }
}

// ---------- RoPE (in-place on bf16, f32 freqs; oscale folds attn scale into q) ----------
__global__ __launch_bounds__(256) void rope_kernel(
    unsigned short* __restrict__ x,
    const float* __restrict__ cs,
    const float* __restrict__ sn,
    int H, int total, float oscale)
{
    int e = blockIdx.x * blockDim.x + threadIdx.x;
    if (e >= total) return;
    int i = e & 63;
    int s = (e / (64 * H)) & 2047;   // S = 2048
    float xr = b2f(x[2 * e]);
    float xi = b2f(x[2 * e + 1]);
    float c  = cs[s * 64 + i];
    float sv = sn[s * 64 + i];
    x[2 * e]     = f2b((xr * c - xi * sv) * oscale);
    x[2 * e + 1] = f2b((xr * sv + xi * c) * oscale);
}

// ---------- MFMA flash attention v3 ----------
// 1024 blocks x 128 threads (2 waves). Block = (b,h) x one 64-row q-tile.
// Wave = 32 Q-rows (2 rowblocks sharing all K/V LDS reads and staging).
// Double-buffered K (DMA) / V (split load->compute->store), ONE barrier/tile.
// PV key permutation key(l)=(l>>1)+16*(l&1): QK^T packed pairs ARE the PV B-frag.
// No running max; Q pre-scaled by (1/sqrt(128))*log2(e); exp2 domain.
__global__ __launch_bounds__(128, 2) void flash_attn(
    const unsigned short* __restrict__ qg,
    const unsigned short* __restrict__ kk,
    const unsigned short* __restrict__ vv,
    unsigned short* __restrict__ out)
{
    const int S = 2048;
    int bid = blockIdx.x;
    int qp  = bid & 31;
    int bh  = bid >> 5;            // b*16 + h
    int h   = bh & 15;
    int b   = bh >> 4;
    int kvh = h >> 2;
    int qt  = (qp & 1) ? (31 - (qp >> 1)) : (qp >> 1);   // heavy/light interleave
    int q0  = qt * 64;

    int tid  = threadIdx.x;
    int w    = tid >> 6;
    int lane = tid & 63;
    int idx  = lane & 15;
    int quad = lane >> 4;
    int wq0  = q0 + w * 32;

    __shared__ unsigned short Ks[2][32 * 128];   // XOR-chunk-swizzled rows
    __shared__ unsigned short Vt[2][128 * 40];   // V^T, key-pair permuted

    const unsigned short* kbase = kk + ((size_t)b * S * 4 + kvh) * 128;
    const unsigned short* vbase = vv + ((size_t)b * S * 4 + kvh) * 128;

    // Q fragments, 2 rowblocks
    bf16x8 qf[2][4];
    #pragma unroll
    for (int rb = 0; rb < 2; ++rb) {
        const unsigned short* qpp =
            qg + ((size_t)((b * S + wq0 + rb * 16 + idx) * 16 + h)) * 128 + quad * 8;
        #pragma unroll
        for (int ko = 0; ko < 4; ++ko)
            qf[rb][ko] = *(const bf16x8*)(qpp + ko * 32);
    }

    f32x4 acc[2][8];
    #pragma unroll
    for (int rb = 0; rb < 2; ++rb)
        #pragma unroll
        for (int n = 0; n < 8; ++n) acc[rb][n] = (f32x4){0.f, 0.f, 0.f, 0.f};
    float lsum[2] = {0.f, 0.f};

    int nt = 2 * qt + 2;

    // V staging geometry: 128 threads cover 64 d-pairs x 2 jb each
    int dp  = (tid & 63) * 2;
    int jb0 = (tid >> 6) * 2;
    unsigned int vld[2][8];

    // ---- prologue: stage tile 0 into buffer 0 ----
    #pragma unroll
    for (int it = 0; it < 4; ++it) {
        int i   = w * 4 + it;
        int key = i * 4 + (lane >> 4);
        int sc  = (lane & 15) ^ (key & 7);
        async_copy16(kbase + (size_t)key * 512 + sc * 8, &Ks[0][i * 512]);
    }
    #pragma unroll
    for (int m = 0; m < 2; ++m) {
        const unsigned short* vc = vbase + ((size_t)(jb0 + m) * 4) * 512 + dp;
        #pragma unroll
        for (int i = 0; i < 8; ++i) {
            int key = (i >> 1) + 16 * (i & 1);
            vld[m][i] = *(const unsigned int*)(vc + key * 512);
        }
    }
    #pragma unroll
    for (int m = 0; m < 2; ++m) {
        u16x8 lo, hi;
        #pragma unroll
        for (int i = 0; i < 8; ++i) {
            lo[i] = (unsigned short)vld[m][i];
            hi[i] = (unsigned short)(vld[m][i] >> 16);
        }
        *(u16x8*)&Vt[0][dp * 40 + (jb0 + m) * 8]       = lo;
        *(u16x8*)&Vt[0][(dp + 1) * 40 + (jb0 + m) * 8] = hi;
    }

    for (int t = 0; t < nt; ++t) {
        int buf = t & 1;
        __syncthreads();   // staging of buf complete; all reads of other buf done

        // ---- issue next tile's loads (latency hidden by compute below) ----
        if (t + 1 < nt) {
            int nbuf = buf ^ 1;
            #pragma unroll
            for (int it = 0; it < 4; ++it) {
                int i   = w * 4 + it;
                int key = i * 4 + (lane >> 4);
                int sc  = (lane & 15) ^ (key & 7);
                async_copy16(kbase + ((size_t)((t + 1) * 32 + key)) * 512 + sc * 8,
                             &Ks[nbuf][i * 512]);
            }
            #pragma unroll
            for (int m = 0; m < 2; ++m) {
                const unsigned short* vc =
                    vbase + ((size_t)((t + 1) * 32 + (jb0 + m) * 4)) * 512 + dp;
                #pragma unroll
                for (int i = 0; i < 8; ++i) {
                    int key = (i >> 1) + 16 * (i & 1);
                    vld[m][i] = *(const unsigned int*)(vc + key * 512);
                }
            }
        }

        // ---- compute tile t ----
        if (t * 32 <= wq0 + 31) {
            f32x4 s00 = {0.f,0.f,0.f,0.f}, s01 = {0.f,0.f,0.f,0.f};
            f32x4 s10 = {0.f,0.f,0.f,0.f}, s11 = {0.f,0.f,0.f,0.f};
            #pragma unroll
            for (int ko = 0; ko < 4; ++ko) {
                int kc = ko * 4 + quad;
                bf16x8 kf0 = *(const bf16x8*)&Ks[buf][idx * 128 + ((kc ^ (idx & 7)) * 8)];
                bf16x8 kf1 = *(const bf16x8*)&Ks[buf][(16 + idx) * 128 + ((kc ^ (idx & 7)) * 8)];
                s00 = MFMA16(kf0, qf[0][ko], s00);
                s01 = MFMA16(kf1, qf[0][ko], s01);
                s10 = MFMA16(kf0, qf[1][ko], s10);
                s11 = MFMA16(kf1, qf[1][ko], s11);
            }
            bf16x8 pf[2];
            #pragma unroll
            for (int rb = 0; rb < 2; ++rb) {
                f32x4 sa = rb ? s10 : s00;
                f32x4 sb = rb ? s11 : s01;
                unsigned int pk[4];
                if (t * 32 + 31 <= wq0 + rb * 16) {        // full tile (uniform)
                    #pragma unroll
                    for (int r = 0; r < 4; ++r) {
                        float p0 = exp2f(sa[r]);
                        float p1 = exp2f(sb[r]);
                        lsum[rb] += p0 + p1;
                        pk[r] = (unsigned int)f2b(p0) | ((unsigned int)f2b(p1) << 16);
                    }
                } else {                                    // diagonal tile
                    int L = wq0 + rb * 16 + idx - t * 32;
                    #pragma unroll
                    for (int r = 0; r < 4; ++r) {
                        int kl = quad * 4 + r;
                        float p0 = (kl      <= L) ? exp2f(sa[r]) : 0.f;
                        float p1 = (kl + 16 <= L) ? exp2f(sb[r]) : 0.f;
                        lsum[rb] += p0 + p1;
                        pk[r] = (unsigned int)f2b(p0) | ((unsigned int)f2b(p1) << 16);
                    }
                }
                u32x4 pku = {pk[0], pk[1], pk[2], pk[3]};
                pf[rb] = __builtin_bit_cast(bf16x8, pku);
            }
            #pragma unroll
            for (int n = 0; n < 8; ++n) {
                bf16x8 vf = *(const bf16x8*)&Vt[buf][(n * 16 + idx) * 40 + quad * 8];
                acc[0][n] = MFMA16(vf, pf[0], acc[0][n]);
                acc[1][n] = MFMA16(vf, pf[1], acc[1][n]);
            }
        }

        // ---- finish next tile's V staging (after compute; before barrier) ----
        if (t + 1 < nt) {
            int nbuf = buf ^ 1;
            #pragma unroll
            for (int m = 0; m < 2; ++m) {
                u16x8 lo, hi;
                #pragma unroll
                for (int i = 0; i < 8; ++i) {
                    lo[i] = (unsigned short)vld[m][i];
                    hi[i] = (unsigned short)(vld[m][i] >> 16);
                }
                *(u16x8*)&Vt[nbuf][dp * 40 + (jb0 + m) * 8]       = lo;
                *(u16x8*)&Vt[nbuf][(dp + 1) * 40 + (jb0 + m) * 8] = hi;
            }
        }
    }

    // ---- epilogue ----
    #pragma unroll
    for (int rb = 0; rb < 2; ++rb) {
        float ls = lsum[rb];
        ls += __shfl_xor(ls, 16);
        ls += __shfl_xor(ls, 32);
        float inv = 1.f / ls;
        size_t rowb = (size_t)(b * S + wq0 + rb * 16 + idx) * 2048 + h * 128;
        #pragma unroll
        for (int n = 0; n < 8; ++n) {
            ushort4 o;
            o.x = f2b(acc[rb][n][0] * inv);
            o.y = f2b(acc[rb][n][1] * inv);
            o.z = f2b(acc[rb][n][2] * inv);
            o.w = f2b(acc[rb][n][3] * inv);
            *(ushort4*)&out[rowb + n * 16 + quad * 4] = o;
        }
    }
}

// ---------- launch ----------
extern "C" void kernel_launch(void* const* d_in, const int* in_sizes, int n_in,
                              void* d_out, int out_size, void* d_ws, size_t ws_size,
                              hipStream_t stream)
{
    const float* x  = (const float*)d_in[0];
    const float* fc = (const float*)d_in[1];
    const float* fs = (const float*)d_in[2];
    const float* wq = (const float*)d_in[3];
    const float* wk = (const float*)d_in[4];
    const float* wv = (const float*)d_in[5];
    const float* wo = (const float*)d_in[6];
    float* out = (float*)d_out;

    const int B = 2, S = 2048, D = 2048, KV = 512;
    const int M = B * S;                 // 4096

    unsigned short* ws  = (unsigned short*)d_ws;
    unsigned short* xb  = ws;                         // 4096*2048
    unsigned short* wqb = xb  + (size_t)M * D;        // 2048*2048
    unsigned short* wkb = wqb + (size_t)D * D;        // 512*2048
    unsigned short* wvb = wkb + (size_t)KV * D;       // 512*2048
    unsigned short* wob = wvb + (size_t)KV * D;       // 2048*2048
    unsigned short* qb  = wob + (size_t)D * D;        // 4096*2048
    unsigned short* kb  = qb  + (size_t)M * D;        // 4096*512
    unsigned short* vb  = kb  + (size_t)M * KV;       // 4096*512
    unsigned short* ao  = vb  + (size_t)M * KV;       // 4096*2048

    cvt_f32_to_bf16<<<dim3((M * D / 4) / 256), dim3(256), 0, stream>>>(x,  xb,  M * D / 4);
    cvt_f32_to_bf16<<<dim3((D * D / 4) / 256), dim3(256), 0, stream>>>(wq, wqb, D * D / 4);
    cvt_f32_to_bf16<<<dim3((KV * D / 4) / 256), dim3(256), 0, stream>>>(wk, wkb, KV * D / 4);
    cvt_f32_to_bf16<<<dim3((KV * D / 4) / 256), dim3(256), 0, stream>>>(wv, wvb, KV * D / 4);
    cvt_f32_to_bf16<<<dim3((D * D / 4) / 256), dim3(256), 0, stream>>>(wo, wob, D * D / 4);

    // fused QKV projection: 32 m-tiles x 24 n-tiles = 768 blocks
    qkv_gemm<<<dim3(768), dim3(256), 0, stream>>>(xb, wqb, wkb, wvb, qb, kb, vb);

    int qpairs = B * S * 16 * 64;
    int kpairs = B * S * 4 * 64;
    const float c2 = 0.12752584f;   // (1/sqrt(128)) * log2(e), folded into q
    rope_kernel<<<dim3(qpairs / 256), dim3(256), 0, stream>>>(qb, fc, fs, 16, qpairs, c2);
    rope_kernel<<<dim3(kpairs / 256), dim3(256), 0, stream>>>(kb, fc, fs, 4, kpairs, 1.0f);

    // flash attention: 1024 blocks x 128 threads, 4 blocks/CU
    flash_attn<<<dim3(1024), dim3(128), 0, stream>>>(qb, kb, vb, ao);

    gemm_tile<float><<<dim3((M / 128) * (D / 128)), dim3(256), 0, stream>>>(ao, wob, out, M, D, D);
}

// Round 8
// 338.781 us; speedup vs baseline: 1.0616x; 1.0616x over previous
//
#include <hip/hip_runtime.h>
#include <hip/hip_bf16.h>
#include <type_traits>

// ---------- types / helpers ----------
using bf16x8 = __attribute__((ext_vector_type(8))) short;   // 8 bf16 in 4 VGPRs
using f32x4  = __attribute__((ext_vector_type(4))) float;
using u16x8  = __attribute__((ext_vector_type(8))) unsigned short;
using u16x4  = __attribute__((ext_vector_type(4))) unsigned short;
using u32x4  = __attribute__((ext_vector_type(4))) unsigned int;

__device__ __forceinline__ float b2f(unsigned short u) {
    unsigned int x = ((unsigned int)u) << 16;
    return __builtin_bit_cast(float, x);
}
__device__ __forceinline__ unsigned short f2b(float f) {
    __hip_bfloat16 h = __float2bfloat16(f);   // RN
    return __builtin_bit_cast(unsigned short, h);
}

// async global->LDS, 16 B per lane; LDS dest is wave-uniform base + lane*16
__device__ __forceinline__ void async_copy16(const void* g, void* l) {
    __builtin_amdgcn_global_load_lds(
        (const __attribute__((address_space(1))) unsigned int*)g,
        (__attribute__((address_space(3))) unsigned int*)l, 16, 0, 0);
}

#define MFMA16(a, b, c) __builtin_amdgcn_mfma_f32_16x16x32_bf16(a, b, c, 0, 0, 0)

// ---------- f32 -> bf16 conversion (4 elems/thread) ----------
__global__ __launch_bounds__(256) void cvt_f32_to_bf16(
    const float* __restrict__ s, unsigned short* __restrict__ d, int n4)
{
    int i = blockIdx.x * blockDim.x + threadIdx.x;
    if (i >= n4) return;
    float4 v = ((const float4*)s)[i];
    ushort4 o;
    o.x = f2b(v.x); o.y = f2b(v.y); o.z = f2b(v.z); o.w = f2b(v.w);
    ((ushort4*)d)[i] = o;
}

// ---------- fused QKV GEMM: [Q|K|V] = x @ [wq;wk;wv]^T ----------
__global__ __launch_bounds__(256) void qkv_gemm(
    const unsigned short* __restrict__ A,    // M x 2048
    const unsigned short* __restrict__ Wq,   // 2048 x 2048
    const unsigned short* __restrict__ Wk,   // 512 x 2048
    const unsigned short* __restrict__ Wv,   // 512 x 2048
    unsigned short* __restrict__ Q,          // M x 2048
    unsigned short* __restrict__ Kk,         // M x 512
    unsigned short* __restrict__ V)          // M x 512
{
    const int K = 2048;
    constexpr int BK = 64;
    __shared__ unsigned short As[128 * BK];
    __shared__ unsigned short Bs[128 * BK];

    int tid  = threadIdx.x;
    int w    = tid >> 6;
    int lane = tid & 63;
    int idx  = lane & 15;
    int quad = lane >> 4;
    int wm   = (w >> 1) * 64;
    int wn   = (w & 1) * 64;

    int bm = blockIdx.x / 24;
    int bn = blockIdx.x - bm * 24;
    int m0 = bm * 128;

    const unsigned short* Bt;
    unsigned short* C;
    int Nc, n0;
    if (bn < 16)      { Bt = Wq + (size_t)bn * 128 * K;        C = Q;  Nc = 2048; n0 = bn * 128; }
    else if (bn < 20) { Bt = Wk + (size_t)(bn - 16) * 128 * K; C = Kk; Nc = 512;  n0 = (bn - 16) * 128; }
    else              { Bt = Wv + (size_t)(bn - 20) * 128 * K; C = V;  Nc = 512;  n0 = (bn - 20) * 128; }

    int srow   = lane >> 3;
    int schunk = (lane & 7) ^ srow;

    f32x4 acc[4][4];
    #pragma unroll
    for (int mi = 0; mi < 4; ++mi)
        #pragma unroll
        for (int ni = 0; ni < 4; ++ni) acc[mi][ni] = (f32x4){0.f, 0.f, 0.f, 0.f};

    for (int k0 = 0; k0 < K; k0 += BK) {
        #pragma unroll
        for (int i = 0; i < 4; ++i) {
            int cb = w * 4 + i;
            size_t goff = (size_t)(cb * 8 + srow) * K + k0 + schunk * 8;
            async_copy16(A + (size_t)m0 * K + goff, &As[cb * 512]);
            async_copy16(Bt + goff, &Bs[cb * 512]);
        }
        __syncthreads();

        #pragma unroll
        for (int ks = 0; ks < 2; ++ks) {
            bf16x8 af[4], bfr[4];
            #pragma unroll
            for (int mi = 0; mi < 4; ++mi) {
                int row = wm + mi * 16 + idx;
                af[mi] = *(const bf16x8*)&As[row * BK + (((ks * 4 + quad) ^ (row & 7)) * 8)];
            }
            #pragma unroll
            for (int ni = 0; ni < 4; ++ni) {
                int row = wn + ni * 16 + idx;
                bfr[ni] = *(const bf16x8*)&Bs[row * BK + (((ks * 4 + quad) ^ (row & 7)) * 8)];
            }
            #pragma unroll
            for (int mi = 0; mi < 4; ++mi)
                #pragma unroll
                for (int ni = 0; ni < 4; ++ni)
                    acc[mi][ni] = MFMA16(af[mi], bfr[ni], acc[mi][ni]);
        }
        __syncthreads();
    }

    #pragma unroll
    for (int mi = 0; mi < 4; ++mi) {
        #pragma unroll
        for (int r = 0; r < 4; ++r) {
            size_t row = (size_t)(m0 + wm + mi * 16 + quad * 4 + r);
            #pragma unroll
            for (int ni = 0; ni < 4; ++ni) {
                int col = n0 + wn + ni * 16 + idx;
                C[row * Nc + col] = f2b(acc[mi][ni][r]);
            }
        }
    }
}

// ---------- tiled GEMM: C[M,N] = A[M,K] * Bt[N,K]^T (wo projection) ----------
template <typename OutT>
__global__ __launch_bounds__(256) void gemm_tile(
    const unsigned short* __restrict__ A,
    const unsigned short* __restrict__ Bt,
    OutT* __restrict__ C,
    int M, int N, int K)
{
    constexpr int BK = 64;
    __shared__ unsigned short As[128 * BK];
    __shared__ unsigned short Bs[128 * BK];

    int tid  = threadIdx.x;
    int w    = tid >> 6;
    int lane = tid & 63;
    int idx  = lane & 15;
    int quad = lane >> 4;
    int wm   = (w >> 1) * 64;
    int wn   = (w & 1) * 64;

    int tilesN = N / 128;
    int bm = blockIdx.x / tilesN;
    int bn = blockIdx.x - bm * tilesN;
    int m0 = bm * 128, n0 = bn * 128;

    int srow   = lane >> 3;
    int schunk = (lane & 7) ^ srow;

    f32x4 acc[4][4];
    #pragma unroll
    for (int mi = 0; mi < 4; ++mi)
        #pragma unroll
        for (int ni = 0; ni < 4; ++ni) acc[mi][ni] = (f32x4){0.f, 0.f, 0.f, 0.f};

    for (int k0 = 0; k0 < K; k0 += BK) {
        #pragma unroll
        for (int i = 0; i < 4; ++i) {
            int cb = w * 4 + i;
            size_t goff = (size_t)(cb * 8 + srow) * K + k0 + schunk * 8;
            async_copy16(A  + (size_t)m0 * K + goff, &As[cb * 512]);
            async_copy16(Bt + (size_t)n0 * K + goff, &Bs[cb * 512]);
        }
        __syncthreads();

        #pragma unroll
        for (int ks = 0; ks < 2; ++ks) {
            bf16x8 af[4], bfr[4];
            #pragma unroll
            for (int mi = 0; mi < 4; ++mi) {
                int row = wm + mi * 16 + idx;
                af[mi] = *(const bf16x8*)&As[row * BK + (((ks * 4 + quad) ^ (row & 7)) * 8)];
            }
            #pragma unroll
            for (int ni = 0; ni < 4; ++ni) {
                int row = wn + ni * 16 + idx;
                bfr[ni] = *(const bf16x8*)&Bs[row * BK + (((ks * 4 + quad) ^ (row & 7)) * 8)];
            }
            #pragma unroll
            for (int mi = 0; mi < 4; ++mi)
                #pragma unroll
                for (int ni = 0; ni < 4; ++ni)
                    acc[mi][ni] = MFMA16(af[mi], bfr[ni], acc[mi][ni]);
        }
        __syncthreads();
    }

    #pragma unroll
    for (int mi = 0; mi < 4; ++mi) {
        #pragma unroll
        for (int r = 0; r < 4; ++r) {
            size_t row = (size_t)(m0 + wm + mi * 16 + quad * 4 + r);
            #pragma unroll
            for (int ni = 0; ni < 4; ++ni) {
                int col = n0 + wn + ni * 16 + idx;
                if constexpr (std::is_same_v<OutT, float>) {
                    C[row * N + col] = acc[mi][ni][r];
                } else {
                    C[row * N + col] = f2b(acc[mi][ni][r]);
                }
            }
        }
    }
}

// ---------- RoPE (in-place on bf16, f32 freqs; oscale folds attn scale into q) ----------
__global__ __launch_bounds__(256) void rope_kernel(
    unsigned short* __restrict__ x,
    const float* __restrict__ cs,
    const float* __restrict__ sn,
    int H, int total, float oscale)
{
    int e = blockIdx.x * blockDim.x + threadIdx.x;
    if (e >= total) return;
    int i = e & 63;
    int s = (e / (64 * H)) & 2047;   // S = 2048
    float xr = b2f(x[2 * e]);
    float xi = b2f(x[2 * e + 1]);
    float c  = cs[s * 64 + i];
    float sv = sn[s * 64 + i];
    x[2 * e]     = f2b((xr * c - xi * sv) * oscale);
    x[2 * e + 1] = f2b((xr * sv + xi * c) * oscale);
}

// ---------- MFMA flash attention v4: 512 blocks x 512 threads ----------
// Block = (b,h) x q-tile PAIR (qp, 31-qp); waves 0-3 -> tile qp, waves 4-7 ->
// tile 31-qp, SHARING one K/V staging pass (light tile's keys are a prefix of
// heavy's). Single-buffer, 2 barriers/tile (R6-proven). Uniform block work.
// PV key permutation key(l)=(l>>1)+16*(l&1): QK^T packed pairs ARE the PV B-frag.
// No running max; Q pre-scaled by (1/sqrt(128))*log2(e); exp2 domain.
__global__ __launch_bounds__(512, 4) void flash_attn(
    const unsigned short* __restrict__ qg,
    const unsigned short* __restrict__ kk,
    const unsigned short* __restrict__ vv,
    unsigned short* __restrict__ out)
{
    const int S = 2048;
    int bid = blockIdx.x;
    int qp  = bid & 15;
    int bh  = bid >> 4;            // b*16 + h
    int h   = bh & 15;
    int b   = bh >> 4;
    int kvh = h >> 2;

    int tid  = threadIdx.x;
    int w    = tid >> 6;           // 0..7
    int lane = tid & 63;
    int idx  = lane & 15;
    int quad = lane >> 4;

    int qt  = (w >> 2) ? (31 - qp) : qp;
    int q0  = qt * 64;
    int wq0 = q0 + (w & 3) * 16;
    int qr  = wq0 + idx;

    __shared__ unsigned short Ks[32 * 128];   // XOR-chunk-swizzled rows
    __shared__ unsigned short Vt[128 * 40];   // V^T, key-pair permuted, pad 40

    const unsigned short* kbase = kk + ((size_t)b * S * 4 + kvh) * 128;
    const unsigned short* vbase = vv + ((size_t)b * S * 4 + kvh) * 128;

    // Q fragments (B-operand): lane idx = qrow
    bf16x8 qf[4];
    {
        const unsigned short* qpp =
            qg + ((size_t)((b * S + wq0 + idx) * 16 + h)) * 128 + quad * 8;
        #pragma unroll
        for (int ko = 0; ko < 4; ++ko)
            qf[ko] = *(const bf16x8*)(qpp + ko * 32);
    }

    f32x4 acc[8];
    #pragma unroll
    for (int n = 0; n < 8; ++n) acc[n] = (f32x4){0.f, 0.f, 0.f, 0.f};
    float lsum = 0.f;

    // V staging geometry: 512 threads cover 64 d-pairs x 4 jb x 2 i-halves
    int dp = (tid & 63) * 2;
    int jb = (tid >> 6) & 3;
    int ih = (tid >> 8) * 4;       // i-half: 0..3 or 4..7

    // heavy tile determines block's iteration count
    int ntA = 2 * qp + 2, ntB = 64 - 2 * qp;
    int nt  = ntA > ntB ? ntA : ntB;

    for (int t = 0; t < nt; ++t) {
        // --- K stage via DMA: wave w stages rows w*4..w*4+3 ---
        {
            int key = w * 4 + (lane >> 4);
            int sc  = (lane & 15) ^ (key & 7);
            async_copy16(kbase + ((size_t)(t * 32 + key)) * 512 + sc * 8,
                         &Ks[w * 512]);
        }
        // --- V stage: transposed + key-pair permuted, b32 coalesced ---
        {
            const unsigned short* vc = vbase + ((size_t)(t * 32 + jb * 4)) * 512 + dp;
            unsigned int ld[4];
            #pragma unroll
            for (int i = 0; i < 4; ++i) {
                int ii  = ih + i;
                int key = (ii >> 1) + 16 * (ii & 1);
                ld[i] = *(const unsigned int*)(vc + key * 512);
            }
            u16x4 lo, hi;
            #pragma unroll
            for (int i = 0; i < 4; ++i) {
                lo[i] = (unsigned short)ld[i];
                hi[i] = (unsigned short)(ld[i] >> 16);
            }
            *(u16x4*)&Vt[dp * 40 + jb * 8 + ih]       = lo;
            *(u16x4*)&Vt[(dp + 1) * 40 + jb * 8 + ih] = hi;
        }
        __syncthreads();

        if (t * 32 <= wq0 + 15) {   // tile within this wave's causal range
            // --- S^T = K·Q^T ---
            f32x4 s0 = {0.f,0.f,0.f,0.f}, s1 = {0.f,0.f,0.f,0.f};
            #pragma unroll
            for (int ko = 0; ko < 4; ++ko) {
                int kc = ko * 4 + quad;
                bf16x8 kf0 = *(const bf16x8*)&Ks[idx * 128 + ((kc ^ (idx & 7)) * 8)];
                bf16x8 kf1 = *(const bf16x8*)&Ks[(16 + idx) * 128 + ((kc ^ (idx & 7)) * 8)];
                s0 = MFMA16(kf0, qf[ko], s0);
                s1 = MFMA16(kf1, qf[ko], s1);
            }
            // --- mask + exp2 (no max); pk pairs = PV B-frag directly ---
            unsigned int pk[4];
            if (t * 32 + 31 <= wq0) {          // full tile (wave-uniform path)
                #pragma unroll
                for (int r = 0; r < 4; ++r) {
                    float p0 = exp2f(s0[r]);
                    float p1 = exp2f(s1[r]);
                    lsum += p0 + p1;
                    pk[r] = (unsigned int)f2b(p0) | ((unsigned int)f2b(p1) << 16);
                }
            } else {                            // diagonal tile
                int L = qr - t * 32;
                #pragma unroll
                for (int r = 0; r < 4; ++r) {
                    int kl = quad * 4 + r;
                    float p0 = (kl      <= L) ? exp2f(s0[r]) : 0.f;
                    float p1 = (kl + 16 <= L) ? exp2f(s1[r]) : 0.f;
                    lsum += p0 + p1;
                    pk[r] = (unsigned int)f2b(p0) | ((unsigned int)f2b(p1) << 16);
                }
            }
            u32x4 pku = {pk[0], pk[1], pk[2], pk[3]};
            bf16x8 pf = __builtin_bit_cast(bf16x8, pku);
            // --- PV: O^T += V^T · P^T ---
            #pragma unroll
            for (int n = 0; n < 8; ++n) {
                bf16x8 vf = *(const bf16x8*)&Vt[(n * 16 + idx) * 40 + quad * 8];
                acc[n] = MFMA16(vf, pf, acc[n]);
            }
        }
        __syncthreads();
    }

    // --- epilogue ---
    lsum += __shfl_xor(lsum, 16);
    lsum += __shfl_xor(lsum, 32);
    float inv = 1.f / lsum;
    size_t rowb = (size_t)(b * S + wq0 + idx) * 2048 + h * 128;
    #pragma unroll
    for (int n = 0; n < 8; ++n) {
        ushort4 o;
        o.x = f2b(acc[n][0] * inv);
        o.y = f2b(acc[n][1] * inv);
        o.z = f2b(acc[n][2] * inv);
        o.w = f2b(acc[n][3] * inv);
        *(ushort4*)&out[rowb + n * 16 + quad * 4] = o;
    }
}

// ---------- launch ----------
extern "C" void kernel_launch(void* const* d_in, const int* in_sizes, int n_in,
                              void* d_out, int out_size, void* d_ws, size_t ws_size,
                              hipStream_t stream)
{
    const float* x  = (const float*)d_in[0];
    const float* fc = (const float*)d_in[1];
    const float* fs = (const float*)d_in[2];
    const float* wq = (const float*)d_in[3];
    const float* wk = (const float*)d_in[4];
    const float* wv = (const float*)d_in[5];
    const float* wo = (const float*)d_in[6];
    float* out = (float*)d_out;

    const int B = 2, S = 2048, D = 2048, KV = 512;
    const int M = B * S;                 // 4096

    unsigned short* ws  = (unsigned short*)d_ws;
    unsigned short* xb  = ws;                         // 4096*2048
    unsigned short* wqb = xb  + (size_t)M * D;        // 2048*2048
    unsigned short* wkb = wqb + (size_t)D * D;        // 512*2048
    unsigned short* wvb = wkb + (size_t)KV * D;       // 512*2048
    unsigned short* wob = wvb + (size_t)KV * D;       // 2048*2048
    unsigned short* qb  = wob + (size_t)D * D;        // 4096*2048
    unsigned short* kb  = qb  + (size_t)M * D;        // 4096*512
    unsigned short* vb  = kb  + (size_t)M * KV;       // 4096*512
    unsigned short* ao  = vb  + (size_t)M * KV;       // 4096*2048

    cvt_f32_to_bf16<<<dim3((M * D / 4) / 256), dim3(256), 0, stream>>>(x,  xb,  M * D / 4);
    cvt_f32_to_bf16<<<dim3((D * D / 4) / 256), dim3(256), 0, stream>>>(wq, wqb, D * D / 4);
    cvt_f32_to_bf16<<<dim3((KV * D / 4) / 256), dim3(256), 0, stream>>>(wk, wkb, KV * D / 4);
    cvt_f32_to_bf16<<<dim3((KV * D / 4) / 256), dim3(256), 0, stream>>>(wv, wvb, KV * D / 4);
    cvt_f32_to_bf16<<<dim3((D * D / 4) / 256), dim3(256), 0, stream>>>(wo, wob, D * D / 4);

    // fused QKV projection: 32 m-tiles x 24 n-tiles = 768 blocks
    qkv_gemm<<<dim3(768), dim3(256), 0, stream>>>(xb, wqb, wkb, wvb, qb, kb, vb);

    int qpairs = B * S * 16 * 64;
    int kpairs = B * S * 4 * 64;
    const float c2 = 0.12752584f;   // (1/sqrt(128)) * log2(e), folded into q
    rope_kernel<<<dim3(qpairs / 256), dim3(256), 0, stream>>>(qb, fc, fs, 16, qpairs, c2);
    rope_kernel<<<dim3(kpairs / 256), dim3(256), 0, stream>>>(kb, fc, fs, 4, kpairs, 1.0f);

    // flash attention: 512 blocks x 512 threads (8 waves, tile-pair sharing)
    flash_attn<<<dim3(512), dim3(512), 0, stream>>>(qb, kb, vb, ao);

    gemm_tile<float><<<dim3((M / 128) * (D / 128)), dim3(256), 0, stream>>>(ao, wob, out, M, D, D);
}